// Round 4
// baseline (270.528 us; speedup 1.0000x reference)
//
#include <hip/hip_runtime.h>
#include <hip/hip_bf16.h>
#include <math.h>

typedef __bf16 bf16x8 __attribute__((ext_vector_type(8)));
typedef float f32x4 __attribute__((ext_vector_type(4)));
typedef unsigned short u16;

#define MROWS 16384   // B*T*P = 2*512*16
#define TT 512
#define PP 16

__device__ __forceinline__ float bf2f(u16 u) {
    union { unsigned int i; float f; } v; v.i = ((unsigned int)u) << 16; return v.f;
}
__device__ __forceinline__ u16 f2bf(float f) {
    union { float f; unsigned int i; } v; v.f = f;
    unsigned int x = v.i;
    return (u16)((x + 0x7FFFu + ((x >> 16) & 1u)) >> 16);
}

// Stage 8 contiguous elements (by element index) from src into dst as bf16.
// f32 path: two float4 loads + RNE convert. bf16 path: one uint4 load.
__device__ __forceinline__ void stage8(u16* dst, const void* src, long idx, bool f32) {
    if (f32) {
        const float4* p = (const float4*)((const float*)src + idx);
        float4 a = p[0], b = p[1];
        u16 t[8] = { f2bf(a.x), f2bf(a.y), f2bf(a.z), f2bf(a.w),
                     f2bf(b.x), f2bf(b.y), f2bf(b.z), f2bf(b.w) };
        *(uint4*)dst = *(const uint4*)t;
    } else {
        *(uint4*)dst = *(const uint4*)((const u16*)src + idx);
    }
}

// ---------------------------------------------------------------------------
// Dtype probe: decide whether inputs are f32 or bf16.
// Even-index u16s of an f32 buffer are uniform-random mantissa words
// (exp field 0x00/0xFF with p~2/256); genuine bf16 N(0,1) values never
// have exp 0xFF or subnormal exp 0x00. Count "impossible" patterns.
// ---------------------------------------------------------------------------
__global__ void probe_k(const u16* __restrict__ x, int* __restrict__ flag) {
    __shared__ int cnt[4];
    int weird = 0;
    #pragma unroll
    for (int j = 0; j < 16; ++j) {
        u16 v = x[(threadIdx.x * 16u + j) * 2u];   // even indices, first 8192 u16s
        int e = (v >> 7) & 0xFF;
        weird += (e == 0xFF || (e == 0 && v != 0)) ? 1 : 0;
    }
    #pragma unroll
    for (int off = 1; off < 64; off <<= 1) weird += __shfl_xor(weird, off, 64);
    if ((threadIdx.x & 63) == 0) cnt[threadIdx.x >> 6] = weird;
    __syncthreads();
    if (threadIdx.x == 0)
        flag[0] = ((cnt[0] + cnt[1] + cnt[2] + cnt[3]) >= 3) ? 1 : 0;  // 1 = f32
}

// ---------------------------------------------------------------------------
// GEMM: C[m][n] = sum_k A[m][k] * W[n][k] (+bias, +RoPE for QKV mode)
// A: MROWS x 512 row-major. W sections: 512x512 row-major (N,K).
// Input dtype steered by *flag (f32 vs bf16). QKV outputs always bf16;
// proj output format follows flag.
// ---------------------------------------------------------------------------
template<bool QKV>
__global__ __launch_bounds__(256, 2)
void gemm_k(const void* __restrict__ A,
            const void* __restrict__ Wq, const void* __restrict__ Wk,
            const void* __restrict__ Wv,
            const void* __restrict__ bq, const void* __restrict__ bk,
            const void* __restrict__ bv,
            const int* __restrict__ flag,
            void* __restrict__ Oq, u16* __restrict__ Ok, u16* __restrict__ Ov)
{
    __shared__ u16 As[128][40];   // 128 x 32, +8 pad; row stride 80B = 5*16B
    __shared__ u16 Bs[128][40];

    const int isf32 = flag[0];
    const bool aF32 = QKV ? (isf32 != 0) : false;   // proj A (=Y) is always bf16
    const bool wF32 = (isf32 != 0);

    const int tid  = threadIdx.x;
    const int wv   = tid >> 6;
    const int lane = tid & 63;
    const int quad = lane >> 4;
    const int l16  = lane & 15;
    const int wm   = wv >> 1, wn = wv & 1;

    const int blockM = blockIdx.x;
    const int blockN = blockIdx.y;

    const void* W; const void* bias; u16* OutB;
    int ncol0;
    if constexpr (QKV) {
        const int section = blockN >> 2;
        ncol0 = (blockN & 3) * 128;
        W    = (section == 0) ? Wq : (section == 1) ? Wk : Wv;
        bias = (section == 0) ? bq : (section == 1) ? bk : bv;
        OutB = (section == 0) ? (u16*)Oq : (section == 1) ? Ok : Ov;
    } else {
        ncol0 = blockN * 128;
        W = Wq; bias = nullptr; OutB = (u16*)Oq;
    }

    f32x4 acc[4][4] = {};

    const int ra = tid >> 2;              // rows 0..63
    const int ca = (tid & 3) * 8;         // element chunk (8 elems)

    for (int kk = 0; kk < 16; ++kk) {
        const int k0 = kk * 32;
        __syncthreads();
        stage8(&As[ra     ][ca], A, (long)(blockM*128 + ra     ) * 512 + k0 + ca, aF32);
        stage8(&As[ra + 64][ca], A, (long)(blockM*128 + ra + 64) * 512 + k0 + ca, aF32);
        stage8(&Bs[ra     ][ca], W, (long)(ncol0     + ra     ) * 512 + k0 + ca, wF32);
        stage8(&Bs[ra + 64][ca], W, (long)(ncol0     + ra + 64) * 512 + k0 + ca, wF32);
        __syncthreads();

        bf16x8 af[4], bfr[4];
        #pragma unroll
        for (int ms = 0; ms < 4; ++ms)
            af[ms] = *(const bf16x8*)&As[wm*64 + ms*16 + l16][quad*8];
        #pragma unroll
        for (int ns = 0; ns < 4; ++ns)
            bfr[ns] = *(const bf16x8*)&Bs[wn*64 + ns*16 + l16][quad*8];
        #pragma unroll
        for (int ms = 0; ms < 4; ++ms)
            #pragma unroll
            for (int ns = 0; ns < 4; ++ns)
                acc[ms][ns] = __builtin_amdgcn_mfma_f32_16x16x32_bf16(af[ms], bfr[ns], acc[ms][ns], 0, 0, 0);
    }

    // epilogue: bias + RoPE, bf16 store (QKV) or flag-format store (proj)
    #pragma unroll
    for (int ms = 0; ms < 4; ++ms) {
        const int g_m0 = blockM*128 + wm*64 + ms*16 + quad*4;
        #pragma unroll
        for (int ns = 0; ns < 4; ++ns) {
            const int n_local = ncol0 + wn*64 + ns*16 + l16;   // 0..511 within section
            float bval = 0.f;
            if constexpr (QKV)
                bval = wF32 ? ((const float*)bias)[n_local] : bf2f(((const u16*)bias)[n_local]);
            #pragma unroll
            for (int r = 0; r < 4; ++r) {
                float val = acc[ms][ns][r] + bval;
                float partner = __shfl_xor(val, 1, 64);   // pair column (d^1) = lane^1
                if constexpr (QKV) {
                    if (blockN < 8) {   // q or k section: RoPE (block-uniform branch)
                        const int m = g_m0 + r;
                        const int t = (m >> 4) & 511;     // m = (b*T + t)*P + p
                        const int d = n_local & 63;
                        float ang = (float)t * __expf(-(float)(d & ~1) * (9.210340371976184f / 64.0f));
                        float s_, c_;
                        __sincosf(ang, &s_, &c_);
                        val = (d & 1) ? (val * c_ + partner * s_)
                                      : (val * c_ - partner * s_);
                    }
                }
                const size_t off = (size_t)(g_m0 + r) * 512 + n_local;
                if constexpr (QKV) {
                    OutB[off] = f2bf(val);
                } else {
                    if (isf32) ((float*)Oq)[off] = val;
                    else       ((u16*)Oq)[off]  = f2bf(val);
                }
            }
        }
    }
}

// ---------------------------------------------------------------------------
// Causal attention per (b,p,h) over T=512, D=64. grid (4 q-tiles, 256 heads).
// Q/K/V: bf16, row m=(b*T+t)*P+p, col h*64+d. Y aliases Q (disjoint
// per-block regions; Q read into LDS before any Y store in that block).
// ---------------------------------------------------------------------------
__global__ __launch_bounds__(256, 2)
void attn_k(const u16* __restrict__ Q, const u16* __restrict__ K,
            const u16* __restrict__ V, u16* __restrict__ Y)
{
    __shared__ u16 Qs[128][72];
    __shared__ u16 Ks[64][72];
    __shared__ u16 Vt[64][72];    // transposed: [d][u]
    __shared__ u16 Ps[128][72];

    const int tid  = threadIdx.x;
    const int wv   = tid >> 6;
    const int lane = tid & 63;
    const int quad = lane >> 4;
    const int l16  = lane & 15;

    const int qt  = blockIdx.x;          // 0..3
    const int hid = blockIdx.y;          // 0..255
    const int b = hid >> 7;
    const int p = (hid >> 3) & 15;
    const int h = hid & 7;

    const int t0 = qt * 128;
    const int base = ((b * TT) * PP + p) * 512 + h * 64;
    const int rowStride = PP * 512;      // 8192

    #pragma unroll
    for (int i = 0; i < 4; ++i) {
        int task = tid + i * 256;          // 0..1023
        int row = task >> 3, c = (task & 7) * 8;
        *(uint4*)&Qs[row][c] = *(const uint4*)&Q[base + (t0 + row) * rowStride + c];
    }

    float m_i[8], l_i[8], alpha[8];
    f32x4 o[2][4] = {};
    #pragma unroll
    for (int j = 0; j < 8; ++j) { m_i[j] = -3.0e38f; l_i[j] = 0.f; }

    const int nUT = (qt + 1) * 2;
    for (int ui = 0; ui < nUT; ++ui) {
        const int u0 = ui * 64;
        __syncthreads();
        #pragma unroll
        for (int i = 0; i < 2; ++i) {
            int task = tid + i * 256;      // 0..511
            int row = task >> 3, c = (task & 7) * 8;
            *(uint4*)&Ks[row][c] = *(const uint4*)&K[base + (u0 + row) * rowStride + c];
        }
        #pragma unroll
        for (int i = 0; i < 4; ++i) {
            int task = tid + i * 256;
            int u = task >> 4, dc = (task & 15) * 4;
            uint2 vvv = *(const uint2*)&V[base + (u0 + u) * rowStride + dc];
            Vt[dc + 0][u] = (u16)(vvv.x & 0xFFFF);
            Vt[dc + 1][u] = (u16)(vvv.x >> 16);
            Vt[dc + 2][u] = (u16)(vvv.y & 0xFFFF);
            Vt[dc + 3][u] = (u16)(vvv.y >> 16);
        }
        __syncthreads();

        // S = Q K^T
        f32x4 s[2][4] = {};
        #pragma unroll
        for (int ks = 0; ks < 2; ++ks) {
            bf16x8 aq[2], bk_[4];
            #pragma unroll
            for (int ms = 0; ms < 2; ++ms)
                aq[ms] = *(const bf16x8*)&Qs[wv*32 + ms*16 + l16][ks*32 + quad*8];
            #pragma unroll
            for (int ns = 0; ns < 4; ++ns)
                bk_[ns] = *(const bf16x8*)&Ks[ns*16 + l16][ks*32 + quad*8];
            #pragma unroll
            for (int ms = 0; ms < 2; ++ms)
                #pragma unroll
                for (int ns = 0; ns < 4; ++ns)
                    s[ms][ns] = __builtin_amdgcn_mfma_f32_16x16x32_bf16(aq[ms], bk_[ns], s[ms][ns], 0, 0, 0);
        }
        #pragma unroll
        for (int ms = 0; ms < 2; ++ms)
            #pragma unroll
            for (int ns = 0; ns < 4; ++ns)
                #pragma unroll
                for (int r = 0; r < 4; ++r) {
                    int trow = t0 + wv*32 + ms*16 + quad*4 + r;
                    int ucol = u0 + ns*16 + l16;
                    float v = s[ms][ns][r] * 0.125f;
                    s[ms][ns][r] = (ucol > trow) ? -1.0e30f : v;
                }
        // online softmax: wave owns its 32 rows; reduce across l16 only
        #pragma unroll
        for (int ms = 0; ms < 2; ++ms) {
            #pragma unroll
            for (int r = 0; r < 4; ++r) {
                const int j = ms*4 + r;
                float tmax = s[ms][0][r];
                #pragma unroll
                for (int ns = 1; ns < 4; ++ns) tmax = fmaxf(tmax, s[ms][ns][r]);
                #pragma unroll
                for (int off = 1; off < 16; off <<= 1)
                    tmax = fmaxf(tmax, __shfl_xor(tmax, off, 64));
                float mn = fmaxf(m_i[j], tmax);
                alpha[j] = __expf(fminf(m_i[j] - mn, 0.f));
                m_i[j] = mn;
                float rsum = 0.f;
                #pragma unroll
                for (int ns = 0; ns < 4; ++ns) {
                    float e = __expf(fminf(s[ms][ns][r] - mn, 0.f));
                    s[ms][ns][r] = e;
                    rsum += e;
                }
                #pragma unroll
                for (int off = 1; off < 16; off <<= 1)
                    rsum += __shfl_xor(rsum, off, 64);
                l_i[j] = l_i[j] * alpha[j] + rsum;
            }
        }
        #pragma unroll
        for (int ms = 0; ms < 2; ++ms)
            #pragma unroll
            for (int nd = 0; nd < 4; ++nd)
                #pragma unroll
                for (int r = 0; r < 4; ++r)
                    o[ms][nd][r] *= alpha[ms*4 + r];
        #pragma unroll
        for (int ms = 0; ms < 2; ++ms)
            #pragma unroll
            for (int ns = 0; ns < 4; ++ns)
                #pragma unroll
                for (int r = 0; r < 4; ++r)
                    Ps[wv*32 + ms*16 + quad*4 + r][ns*16 + l16] = f2bf(s[ms][ns][r]);
        __syncthreads();
        #pragma unroll
        for (int ks = 0; ks < 2; ++ks) {
            bf16x8 ap[2], bv_[4];
            #pragma unroll
            for (int ms = 0; ms < 2; ++ms)
                ap[ms] = *(const bf16x8*)&Ps[wv*32 + ms*16 + l16][ks*32 + quad*8];
            #pragma unroll
            for (int nd = 0; nd < 4; ++nd)
                bv_[nd] = *(const bf16x8*)&Vt[nd*16 + l16][ks*32 + quad*8];
            #pragma unroll
            for (int ms = 0; ms < 2; ++ms)
                #pragma unroll
                for (int nd = 0; nd < 4; ++nd)
                    o[ms][nd] = __builtin_amdgcn_mfma_f32_16x16x32_bf16(ap[ms], bv_[nd], o[ms][nd], 0, 0, 0);
        }
    }

    #pragma unroll
    for (int ms = 0; ms < 2; ++ms)
        #pragma unroll
        for (int nd = 0; nd < 4; ++nd)
            #pragma unroll
            for (int r = 0; r < 4; ++r) {
                int t = t0 + wv*32 + ms*16 + quad*4 + r;
                int d = nd*16 + l16;
                float val = o[ms][nd][r] / l_i[ms*4 + r];
                int ym = (b * TT + t) * PP + p;
                Y[ym * 512 + h * 64 + d] = f2bf(val);
            }
}

// ---------------------------------------------------------------------------
extern "C" void kernel_launch(void* const* d_in, const int* in_sizes, int n_in,
                              void* d_out, int out_size, void* d_ws, size_t ws_size,
                              hipStream_t stream) {
    const void* x  = d_in[0];
    const void* qw = d_in[1];
    const void* qb = d_in[2];
    const void* kw = d_in[3];
    const void* kb = d_in[4];
    const void* vw = d_in[5];
    const void* vb = d_in[6];
    const void* pw = d_in[7];

    // ws layout: [flag page 1KB][Qb 16MB][Kb 16MB]. V (bf16) lives in d_out
    // (d_out is >= 16MB under either output dtype); its lifetime ends before
    // the proj gemm overwrites d_out. Y aliases Qb.
    int* flag = (int*)d_ws;
    u16* Qb = (u16*)((char*)d_ws + 1024);
    u16* Kb = Qb + (size_t)MROWS * 512;
    u16* Vb = (u16*)d_out;
    u16* Yb = Qb;

    // 0) dtype probe (writes flag: 1 = f32 inputs, 0 = bf16 inputs)
    probe_k<<<1, 256, 0, stream>>>((const u16*)x, flag);
    // 1) fused QKV projection + bias + RoPE (bf16 out)
    gemm_k<true><<<dim3(128, 12), 256, 0, stream>>>(x, qw, kw, vw, qb, kb, vb,
                                                    flag, Qb, Kb, Vb);
    // 2) causal flash attention per (b,p,h)
    attn_k<<<dim3(4, 256), 256, 0, stream>>>(Qb, Kb, Vb, Yb);
    // 3) output projection (output format follows flag)
    gemm_k<false><<<dim3(128, 4), 256, 0, stream>>>(Yb, pw, nullptr, nullptr,
                                                    nullptr, nullptr, nullptr,
                                                    flag, d_out, nullptr, nullptr);
}

// Round 5
// 227.719 us; speedup vs baseline: 1.1880x; 1.1880x over previous
//
#include <hip/hip_runtime.h>
#include <hip/hip_bf16.h>
#include <math.h>

typedef __bf16 bf16x8 __attribute__((ext_vector_type(8)));
typedef float f32x4 __attribute__((ext_vector_type(4)));
typedef unsigned short u16;

#define MROWS 16384   // B*T*P
#define TT 512
#define PP 16

__device__ __forceinline__ u16 f2bf(float f) {
    union { float f; unsigned int i; } v; v.f = f;
    unsigned int x = v.i;
    return (u16)((x + 0x7FFFu + ((x >> 16) & 1u)) >> 16);
}

// async global->LDS, 16B per lane; lds base must be wave-uniform, data lands
// at ldsbase + lane*16 (no per-lane scatter).
__device__ __forceinline__ void async16(const u16* g, u16* lds) {
    __builtin_amdgcn_global_load_lds(
        (const __attribute__((address_space(1))) void*)g,
        (__attribute__((address_space(3))) void*)lds, 16, 0, 0);
}

// ---------------------------------------------------------------------------
// f32 -> bf16 converts (one-shot, memory-bound)
// ---------------------------------------------------------------------------
__global__ __launch_bounds__(256) void cvt_k(const float* __restrict__ s,
                                             u16* __restrict__ d) {
    long i = (long)blockIdx.x * 256 + threadIdx.x;   // per 8 elems, exact grid
    const float4* p = (const float4*)s + i * 2;
    float4 a = p[0], b = p[1];
    u16 t[8] = { f2bf(a.x), f2bf(a.y), f2bf(a.z), f2bf(a.w),
                 f2bf(b.x), f2bf(b.y), f2bf(b.z), f2bf(b.w) };
    *(uint4*)(d + i * 8) = *(const uint4*)t;
}

__global__ __launch_bounds__(256) void cvtw_k(const float* __restrict__ q,
                                              const float* __restrict__ k,
                                              const float* __restrict__ v,
                                              const float* __restrict__ pw,
                                              u16* __restrict__ d) {
    int m = blockIdx.y;
    const float* s = (m == 0) ? q : (m == 1) ? k : (m == 2) ? v : pw;
    long i = (long)blockIdx.x * 256 + threadIdx.x;   // 0..32767 per matrix
    const float4* p = (const float4*)s + i * 2;
    float4 a = p[0], b = p[1];
    u16 t[8] = { f2bf(a.x), f2bf(a.y), f2bf(a.z), f2bf(a.w),
                 f2bf(b.x), f2bf(b.y), f2bf(b.z), f2bf(b.w) };
    *(uint4*)(d + (long)m * 262144 + i * 8) = *(const uint4*)t;
}

// ---------------------------------------------------------------------------
// m97-style GEMM: C[m][n] = sum_k A[m][k]*W[n][k]. BM=BN=128, BK=64.
// A bf16 MROWSx512, W bf16 512x512 (N,K). global_load_lds staging with XOR
// swizzle: chunk (r,c) stored at LDS chunk r*8 + (c ^ (r&7)) -> b128 frag
// reads are bank-balanced, and the DMA's lane*16B layout realizes exactly
// this swizzle when lane l sources chunk col (l&7)^(l>>3).
// QKV mode: grid (128,12), section=blockIdx.y>>2 picks q/k/v; bias f32 +
// RoPE (sections 0,1) epilogue, bf16 out. Proj mode: grid (128,4), f32 out.
// ---------------------------------------------------------------------------
template<bool QKV>
__global__ __launch_bounds__(256, 2)
void gemm_k(const u16* __restrict__ A, const u16* __restrict__ Wall,
            const float* __restrict__ bq, const float* __restrict__ bk,
            const float* __restrict__ bv,
            u16* __restrict__ Oq, u16* __restrict__ Ok, u16* __restrict__ Ov,
            float* __restrict__ Of)
{
    __shared__ u16 As[128 * 64];
    __shared__ u16 Bs[128 * 64];

    const int tid  = threadIdx.x;
    const int wv   = tid >> 6;
    const int lane = tid & 63;
    const int quad = lane >> 4;
    const int l16  = lane & 15;
    const int wm   = wv >> 1, wn = wv & 1;

    const int blockM = blockIdx.x;
    const int blockN = blockIdx.y;

    const u16* W; const float* bias; u16* OutB; int ncol0; int section = 0;
    if constexpr (QKV) {
        section = blockN >> 2;
        ncol0 = (blockN & 3) * 128;
        W    = Wall + (long)section * 262144;
        bias = (section == 0) ? bq : (section == 1) ? bk : bv;
        OutB = (section == 0) ? Oq : (section == 1) ? Ok : Ov;
    } else {
        ncol0 = blockN * 128;
        W = Wall; bias = nullptr; OutB = nullptr;
    }

    const int gm0 = blockM * 128;
    const int lr  = lane >> 3;            // row within 8-row DMA group
    const int lc  = (lane & 7) ^ lr;      // swizzled source chunk col

    f32x4 acc[4][4] = {};

    for (int kk = 0; kk < 8; ++kk) {
        const int k0 = kk * 64;
        __syncthreads();
        #pragma unroll
        for (int i = 0; i < 4; ++i) {
            const int rb = wv * 32 + i * 8;
            async16(&A[(long)(gm0   + rb + lr) * 512 + k0 + lc * 8], &As[rb * 64]);
            async16(&W[(long)(ncol0 + rb + lr) * 512 + k0 + lc * 8], &Bs[rb * 64]);
        }
        __syncthreads();   // includes vmcnt(0) drain of the DMA loads

        #pragma unroll
        for (int ks = 0; ks < 2; ++ks) {
            bf16x8 af[4], bf_[4];
            #pragma unroll
            for (int ms = 0; ms < 4; ++ms) {
                const int R = wm * 64 + ms * 16 + l16;
                af[ms] = *(const bf16x8*)&As[(R * 8 + ((ks * 4 + quad) ^ (l16 & 7))) * 8];
            }
            #pragma unroll
            for (int ns = 0; ns < 4; ++ns) {
                const int R = wn * 64 + ns * 16 + l16;
                bf_[ns] = *(const bf16x8*)&Bs[(R * 8 + ((ks * 4 + quad) ^ (l16 & 7))) * 8];
            }
            #pragma unroll
            for (int ms = 0; ms < 4; ++ms)
                #pragma unroll
                for (int ns = 0; ns < 4; ++ns)
                    acc[ms][ns] = __builtin_amdgcn_mfma_f32_16x16x32_bf16(af[ms], bf_[ns], acc[ms][ns], 0, 0, 0);
        }
    }

    // epilogue
    #pragma unroll
    for (int ms = 0; ms < 4; ++ms) {
        const int g_m0 = gm0 + wm * 64 + ms * 16 + quad * 4;
        #pragma unroll
        for (int ns = 0; ns < 4; ++ns) {
            const int n_local = ncol0 + wn * 64 + ns * 16 + l16;   // 0..511
            float bval = 0.f;
            if constexpr (QKV) bval = bias[n_local];
            #pragma unroll
            for (int r = 0; r < 4; ++r) {
                float val = acc[ms][ns][r] + bval;
                const size_t off = (size_t)(g_m0 + r) * 512 + n_local;
                if constexpr (QKV) {
                    float partner = __shfl_xor(val, 1, 64);   // col d^1 = lane^1
                    if (section < 2) {   // q/k: RoPE (block-uniform branch)
                        const int m = g_m0 + r;
                        const int t = (m >> 4) & 511;         // m=(b*T+t)*P+p
                        const int d = n_local & 63;
                        float ang = (float)t * __expf(-(float)(d & ~1) * (9.210340371976184f / 64.0f));
                        float s_, c_;
                        __sincosf(ang, &s_, &c_);
                        val = (d & 1) ? (val * c_ + partner * s_)
                                      : (val * c_ - partner * s_);
                    }
                    OutB[off] = f2bf(val);
                } else {
                    Of[off] = val;
                }
            }
        }
    }
}

// ---------------------------------------------------------------------------
// Causal flash attention. grid (2, 256): blockIdx.x selects balanced q-tile
// pair {0,3} / {1,2} (10 u-tiles each). Q frags live in registers; Sh hosts
// Q-staging, then K (rows 0..63) and P (all 128 rows) with an extra barrier
// between QK-reads and P-writes. LDS 27.6 KB -> 4 blocks/CU.
// Y aliases Q: per-(hid, t-range) regions are block-exclusive and Q is fully
// consumed into registers before that q-tile's Y store.
// ---------------------------------------------------------------------------
__global__ __launch_bounds__(256, 4)
void attn_k(const u16* __restrict__ Q, const u16* __restrict__ K,
            const u16* __restrict__ V, u16* __restrict__ Y)
{
    __shared__ u16 Sh[128][72];   // Q stage / K (rows 0..63) / P (128 rows)
    __shared__ u16 Vt[64][72];    // V transposed [d][u]

    const int tid  = threadIdx.x;
    const int wv   = tid >> 6;
    const int lane = tid & 63;
    const int quad = lane >> 4;
    const int l16  = lane & 15;

    const int pairx = blockIdx.x;        // 0:{0,3} 1:{1,2}
    const int hid = blockIdx.y;          // 0..255
    const int b = hid >> 7;
    const int p = (hid >> 3) & 15;
    const int h = hid & 7;

    const int base = ((b * TT) * PP + p) * 512 + h * 64;
    const int rowStride = PP * 512;      // 8192

    for (int sel = 0; sel < 2; ++sel) {
        const int qt = (sel == 0) ? pairx : 3 - pairx;
        const int t0 = qt * 128;

        __syncthreads();   // prior q-tile's PV reads of Sh done
        // stage Q tile (128x64): 1024 chunks
        #pragma unroll
        for (int i = 0; i < 4; ++i) {
            int task = tid + i * 256;
            int row = task >> 3, c = (task & 7) * 8;
            *(uint4*)&Sh[row][c] = *(const uint4*)&Q[base + (t0 + row) * rowStride + c];
        }
        __syncthreads();
        bf16x8 qf[2][2];
        #pragma unroll
        for (int ms = 0; ms < 2; ++ms)
            #pragma unroll
            for (int ks = 0; ks < 2; ++ks)
                qf[ms][ks] = *(const bf16x8*)&Sh[wv*32 + ms*16 + l16][ks*32 + quad*8];

        float m_i[8], l_i[8], alpha[8];
        f32x4 o[2][4] = {};
        #pragma unroll
        for (int j = 0; j < 8; ++j) { m_i[j] = -3.0e38f; l_i[j] = 0.f; }

        const int nUT = (qt + 1) * 2;
        for (int ui = 0; ui < nUT; ++ui) {
            const int u0 = ui * 64;
            __syncthreads();   // qf reads / prior PV reads complete
            // stage K (64x64) into Sh rows 0..63
            #pragma unroll
            for (int i = 0; i < 2; ++i) {
                int task = tid + i * 256;
                int row = task >> 3, c = (task & 7) * 8;
                *(uint4*)&Sh[row][c] = *(const uint4*)&K[base + (u0 + row) * rowStride + c];
            }
            // stage V transposed
            #pragma unroll
            for (int i = 0; i < 4; ++i) {
                int task = tid + i * 256;
                int u = task >> 4, dc = (task & 15) * 4;
                uint2 vvv = *(const uint2*)&V[base + (u0 + u) * rowStride + dc];
                Vt[dc + 0][u] = (u16)(vvv.x & 0xFFFF);
                Vt[dc + 1][u] = (u16)(vvv.x >> 16);
                Vt[dc + 2][u] = (u16)(vvv.y & 0xFFFF);
                Vt[dc + 3][u] = (u16)(vvv.y >> 16);
            }
            __syncthreads();

            // S = Q K^T
            f32x4 s[2][4] = {};
            #pragma unroll
            for (int ks = 0; ks < 2; ++ks) {
                bf16x8 bk_[4];
                #pragma unroll
                for (int ns = 0; ns < 4; ++ns)
                    bk_[ns] = *(const bf16x8*)&Sh[ns*16 + l16][ks*32 + quad*8];
                #pragma unroll
                for (int ms = 0; ms < 2; ++ms)
                    #pragma unroll
                    for (int ns = 0; ns < 4; ++ns)
                        s[ms][ns] = __builtin_amdgcn_mfma_f32_16x16x32_bf16(qf[ms][ks], bk_[ns], s[ms][ns], 0, 0, 0);
            }
            __syncthreads();   // all K reads done before P overwrites Sh

            // scale + causal mask
            #pragma unroll
            for (int ms = 0; ms < 2; ++ms)
                #pragma unroll
                for (int ns = 0; ns < 4; ++ns)
                    #pragma unroll
                    for (int r = 0; r < 4; ++r) {
                        int trow = t0 + wv*32 + ms*16 + quad*4 + r;
                        int ucol = u0 + ns*16 + l16;
                        float v = s[ms][ns][r] * 0.125f;
                        s[ms][ns][r] = (ucol > trow) ? -1.0e30f : v;
                    }
            // online softmax (wave-exclusive rows; reduce over l16)
            #pragma unroll
            for (int ms = 0; ms < 2; ++ms) {
                #pragma unroll
                for (int r = 0; r < 4; ++r) {
                    const int j = ms*4 + r;
                    float tmax = s[ms][0][r];
                    #pragma unroll
                    for (int ns = 1; ns < 4; ++ns) tmax = fmaxf(tmax, s[ms][ns][r]);
                    #pragma unroll
                    for (int off = 1; off < 16; off <<= 1)
                        tmax = fmaxf(tmax, __shfl_xor(tmax, off, 64));
                    float mn = fmaxf(m_i[j], tmax);
                    alpha[j] = __expf(fminf(m_i[j] - mn, 0.f));
                    m_i[j] = mn;
                    float rsum = 0.f;
                    #pragma unroll
                    for (int ns = 0; ns < 4; ++ns) {
                        float e = __expf(fminf(s[ms][ns][r] - mn, 0.f));
                        s[ms][ns][r] = e;
                        rsum += e;
                    }
                    #pragma unroll
                    for (int off = 1; off < 16; off <<= 1)
                        rsum += __shfl_xor(rsum, off, 64);
                    l_i[j] = l_i[j] * alpha[j] + rsum;
                }
            }
            #pragma unroll
            for (int ms = 0; ms < 2; ++ms)
                #pragma unroll
                for (int nd = 0; nd < 4; ++nd)
                    #pragma unroll
                    for (int r = 0; r < 4; ++r)
                        o[ms][nd][r] *= alpha[ms*4 + r];
            // write P (C-layout -> row-major in Sh)
            #pragma unroll
            for (int ms = 0; ms < 2; ++ms)
                #pragma unroll
                for (int ns = 0; ns < 4; ++ns)
                    #pragma unroll
                    for (int r = 0; r < 4; ++r)
                        Sh[wv*32 + ms*16 + quad*4 + r][ns*16 + l16] = f2bf(s[ms][ns][r]);
            __syncthreads();
            // O += P @ V
            #pragma unroll
            for (int ks = 0; ks < 2; ++ks) {
                bf16x8 ap[2], bv_[4];
                #pragma unroll
                for (int ms = 0; ms < 2; ++ms)
                    ap[ms] = *(const bf16x8*)&Sh[wv*32 + ms*16 + l16][ks*32 + quad*8];
                #pragma unroll
                for (int nd = 0; nd < 4; ++nd)
                    bv_[nd] = *(const bf16x8*)&Vt[nd*16 + l16][ks*32 + quad*8];
                #pragma unroll
                for (int ms = 0; ms < 2; ++ms)
                    #pragma unroll
                    for (int nd = 0; nd < 4; ++nd)
                        o[ms][nd] = __builtin_amdgcn_mfma_f32_16x16x32_bf16(ap[ms], bv_[nd], o[ms][nd], 0, 0, 0);
            }
        }

        // epilogue for this q-tile
        #pragma unroll
        for (int ms = 0; ms < 2; ++ms)
            #pragma unroll
            for (int nd = 0; nd < 4; ++nd)
                #pragma unroll
                for (int r = 0; r < 4; ++r) {
                    int t = t0 + wv*32 + ms*16 + quad*4 + r;
                    int d = nd*16 + l16;
                    float val = o[ms][nd][r] / l_i[ms*4 + r];
                    int ym = (b * TT + t) * PP + p;
                    Y[ym * 512 + h * 64 + d] = f2bf(val);
                }
    }
}

// ---------------------------------------------------------------------------
extern "C" void kernel_launch(void* const* d_in, const int* in_sizes, int n_in,
                              void* d_out, int out_size, void* d_ws, size_t ws_size,
                              hipStream_t stream) {
    const float* x  = (const float*)d_in[0];
    const float* qw = (const float*)d_in[1];
    const float* qb = (const float*)d_in[2];
    const float* kw = (const float*)d_in[3];
    const float* kb = (const float*)d_in[4];
    const float* vw = (const float*)d_in[5];
    const float* vb = (const float*)d_in[6];
    const float* pw = (const float*)d_in[7];

    // ws (35.7 MB): xb (bf16 x) | wAll (bf16 qw,kw,vw,pw) | Qb.
    // d_out (33.5 MB f32) hosts V (lower 16.8 MB) and K (upper 16.8 MB) as
    // bf16; both dead before the proj GEMM overwrites d_out. Y aliases Qb.
    u16* ws   = (u16*)d_ws;
    u16* xb   = ws;
    u16* wAll = ws + (size_t)MROWS * 512;
    u16* Qb   = wAll + 4 * 262144;
    u16* Vb   = (u16*)d_out;
    u16* Kb   = (u16*)d_out + (size_t)MROWS * 512;

    cvt_k<<<4096, 256, 0, stream>>>(x, xb);
    cvtw_k<<<dim3(128, 4), 256, 0, stream>>>(qw, kw, vw, pw, wAll);
    gemm_k<true><<<dim3(128, 12), 256, 0, stream>>>(xb, wAll, qb, kb, vb,
                                                    Qb, Kb, Vb, nullptr);
    attn_k<<<dim3(2, 256), 256, 0, stream>>>(Qb, Kb, Vb, Qb);
    gemm_k<false><<<dim3(128, 4), 256, 0, stream>>>(Qb, wAll + 3 * 262144,
                                                    nullptr, nullptr, nullptr,
                                                    nullptr, nullptr, nullptr,
                                                    (float*)d_out);
}

// Round 6
// 195.943 us; speedup vs baseline: 1.3806x; 1.1622x over previous
//
#include <hip/hip_runtime.h>
#include <hip/hip_bf16.h>
#include <math.h>

typedef __bf16 bf16x8 __attribute__((ext_vector_type(8)));
typedef float f32x4 __attribute__((ext_vector_type(4)));
typedef unsigned short u16;

#define MROWS 16384   // B*T*P
#define TT 512
#define PP 16

__device__ __forceinline__ u16 f2bf(float f) {
    union { float f; unsigned int i; } v; v.f = f;
    unsigned int x = v.i;
    return (u16)((x + 0x7FFFu + ((x >> 16) & 1u)) >> 16);
}

// async global->LDS, 16B per lane; lds base wave-uniform, data lands at
// ldsbase + lane*16 (no per-lane scatter).
__device__ __forceinline__ void async16(const u16* g, u16* lds) {
    __builtin_amdgcn_global_load_lds(
        (const __attribute__((address_space(1))) void*)g,
        (__attribute__((address_space(3))) void*)lds, 16, 0, 0);
}

// ---------------------------------------------------------------------------
// f32 -> bf16 converts (one-shot, memory-bound)
// ---------------------------------------------------------------------------
__global__ __launch_bounds__(256) void cvt_k(const float* __restrict__ s,
                                             u16* __restrict__ d) {
    long i = (long)blockIdx.x * 256 + threadIdx.x;
    const float4* p = (const float4*)s + i * 2;
    float4 a = p[0], b = p[1];
    u16 t[8] = { f2bf(a.x), f2bf(a.y), f2bf(a.z), f2bf(a.w),
                 f2bf(b.x), f2bf(b.y), f2bf(b.z), f2bf(b.w) };
    *(uint4*)(d + i * 8) = *(const uint4*)t;
}

__global__ __launch_bounds__(256) void cvtw_k(const float* __restrict__ q,
                                              const float* __restrict__ k,
                                              const float* __restrict__ v,
                                              const float* __restrict__ pw,
                                              u16* __restrict__ d) {
    int m = blockIdx.y;
    const float* s = (m == 0) ? q : (m == 1) ? k : (m == 2) ? v : pw;
    long i = (long)blockIdx.x * 256 + threadIdx.x;
    const float4* p = (const float4*)s + i * 2;
    float4 a = p[0], b = p[1];
    u16 t[8] = { f2bf(a.x), f2bf(a.y), f2bf(a.z), f2bf(a.w),
                 f2bf(b.x), f2bf(b.y), f2bf(b.z), f2bf(b.w) };
    *(uint4*)(d + (long)m * 262144 + i * 8) = *(const uint4*)t;
}

// ---------------------------------------------------------------------------
// m97-style GEMM (unchanged from R5): BM=BN=128, BK=64, async16 + XOR swizzle.
// ---------------------------------------------------------------------------
template<bool QKV>
__global__ __launch_bounds__(256, 2)
void gemm_k(const u16* __restrict__ A, const u16* __restrict__ Wall,
            const float* __restrict__ bq, const float* __restrict__ bk,
            const float* __restrict__ bv,
            u16* __restrict__ Oq, u16* __restrict__ Ok, u16* __restrict__ Ov,
            float* __restrict__ Of)
{
    __shared__ u16 As[128 * 64];
    __shared__ u16 Bs[128 * 64];

    const int tid  = threadIdx.x;
    const int wv   = tid >> 6;
    const int lane = tid & 63;
    const int quad = lane >> 4;
    const int l16  = lane & 15;
    const int wm   = wv >> 1, wn = wv & 1;

    const int blockM = blockIdx.x;
    const int blockN = blockIdx.y;

    const u16* W; const float* bias; u16* OutB; int ncol0; int section = 0;
    if constexpr (QKV) {
        section = blockN >> 2;
        ncol0 = (blockN & 3) * 128;
        W    = Wall + (long)section * 262144;
        bias = (section == 0) ? bq : (section == 1) ? bk : bv;
        OutB = (section == 0) ? Oq : (section == 1) ? Ok : Ov;
    } else {
        ncol0 = blockN * 128;
        W = Wall; bias = nullptr; OutB = nullptr;
    }

    const int gm0 = blockM * 128;
    const int lr  = lane >> 3;
    const int lc  = (lane & 7) ^ lr;

    f32x4 acc[4][4] = {};

    for (int kk = 0; kk < 8; ++kk) {
        const int k0 = kk * 64;
        __syncthreads();
        #pragma unroll
        for (int i = 0; i < 4; ++i) {
            const int rb = wv * 32 + i * 8;
            async16(&A[(long)(gm0   + rb + lr) * 512 + k0 + lc * 8], &As[rb * 64]);
            async16(&W[(long)(ncol0 + rb + lr) * 512 + k0 + lc * 8], &Bs[rb * 64]);
        }
        __syncthreads();

        #pragma unroll
        for (int ks = 0; ks < 2; ++ks) {
            bf16x8 af[4], bf_[4];
            #pragma unroll
            for (int ms = 0; ms < 4; ++ms) {
                const int R = wm * 64 + ms * 16 + l16;
                af[ms] = *(const bf16x8*)&As[(R * 8 + ((ks * 4 + quad) ^ (l16 & 7))) * 8];
            }
            #pragma unroll
            for (int ns = 0; ns < 4; ++ns) {
                const int R = wn * 64 + ns * 16 + l16;
                bf_[ns] = *(const bf16x8*)&Bs[(R * 8 + ((ks * 4 + quad) ^ (l16 & 7))) * 8];
            }
            #pragma unroll
            for (int ms = 0; ms < 4; ++ms)
                #pragma unroll
                for (int ns = 0; ns < 4; ++ns)
                    acc[ms][ns] = __builtin_amdgcn_mfma_f32_16x16x32_bf16(af[ms], bf_[ns], acc[ms][ns], 0, 0, 0);
        }
    }

    #pragma unroll
    for (int ms = 0; ms < 4; ++ms) {
        const int g_m0 = gm0 + wm * 64 + ms * 16 + quad * 4;
        #pragma unroll
        for (int ns = 0; ns < 4; ++ns) {
            const int n_local = ncol0 + wn * 64 + ns * 16 + l16;
            float bval = 0.f;
            if constexpr (QKV) bval = bias[n_local];
            #pragma unroll
            for (int r = 0; r < 4; ++r) {
                float val = acc[ms][ns][r] + bval;
                const size_t off = (size_t)(g_m0 + r) * 512 + n_local;
                if constexpr (QKV) {
                    float partner = __shfl_xor(val, 1, 64);
                    if (section < 2) {
                        const int m = g_m0 + r;
                        const int t = (m >> 4) & 511;
                        const int d = n_local & 63;
                        float ang = (float)t * __expf(-(float)(d & ~1) * (9.210340371976184f / 64.0f));
                        float s_, c_;
                        __sincosf(ang, &s_, &c_);
                        val = (d & 1) ? (val * c_ + partner * s_)
                                      : (val * c_ - partner * s_);
                    }
                    OutB[off] = f2bf(val);
                } else {
                    Of[off] = val;
                }
            }
        }
    }
}

// ---------------------------------------------------------------------------
// Causal flash attention, 64-row q-tiles. grid (4, 256): blockIdx.x = pair
// {p, 7-p} -> 9 u-tiles per block (perfect balance), 1024 blocks = 4/CU.
// Sh (8 KB, XOR-swizzled, unpadded for async16 DMA) hosts Q-stage -> K-stage
// -> P per u-tile. Vt (9 KB) holds V^T. Wave wv owns q-rows [wv*16,+16).
// Mask applied only on the diagonal u-tile (block-uniform branch).
// Y aliases Q: per-(hid,qt) regions are block-exclusive; Q is consumed into
// registers before that q-tile's Y store.
// ---------------------------------------------------------------------------
__global__ __launch_bounds__(256, 4)
void attn_k(const u16* __restrict__ Q, const u16* __restrict__ K,
            const u16* __restrict__ V, u16* __restrict__ Y)
{
    __shared__ u16 Sh[64 * 64];   // swizzled: chunk(row,c) at row*8 + (c^(row&7))
    __shared__ u16 Vt[64][72];    // V transposed [d][u] (+8 pad)

    const int tid  = threadIdx.x;
    const int wv   = tid >> 6;
    const int lane = tid & 63;
    const int quad = lane >> 4;
    const int l16  = lane & 15;
    const int lr   = lane >> 3;        // DMA row within 8-row group
    const int lc   = (lane & 7) ^ lr;  // swizzled source chunk col

    const int pairx = blockIdx.x;      // 0..3
    const int hid = blockIdx.y;        // 0..255
    const int b = hid >> 7;
    const int p = (hid >> 3) & 15;
    const int h = hid & 7;

    const int base = ((b * TT) * PP + p) * 512 + h * 64;
    const int rowStride = PP * 512;    // 8192

    for (int sel = 0; sel < 2; ++sel) {
        const int qt = sel ? (7 - pairx) : pairx;   // 64-row q-tile id, 0..7
        const int t0 = qt * 64;

        __syncthreads();   // prior tile's Sh/Vt reads complete
        // stage Q (64x64) swizzled: wave wv stages rows [wv*16, +16)
        #pragma unroll
        for (int i = 0; i < 2; ++i) {
            const int rb = wv * 16 + i * 8;
            async16(&Q[base + (t0 + rb + lr) * rowStride + lc * 8], &Sh[rb * 64]);
        }
        __syncthreads();
        bf16x8 qf[2];
        {
            const int R = wv * 16 + l16;
            #pragma unroll
            for (int ks = 0; ks < 2; ++ks)
                qf[ks] = *(const bf16x8*)&Sh[(R * 8 + ((ks * 4 + quad) ^ (l16 & 7))) * 8];
        }

        float m_i[4], l_i[4], alpha[4];
        f32x4 o[4] = {};
        #pragma unroll
        for (int j = 0; j < 4; ++j) { m_i[j] = -3.0e38f; l_i[j] = 0.f; }

        for (int ui = 0; ui <= qt; ++ui) {
            const int u0 = ui * 64;
            __syncthreads();   // qf read / prior PV+Vt reads complete
            // stage K (64x64) swizzled into Sh
            #pragma unroll
            for (int i = 0; i < 2; ++i) {
                const int rb = wv * 16 + i * 8;
                async16(&K[base + (u0 + rb + lr) * rowStride + lc * 8], &Sh[rb * 64]);
            }
            // stage V transposed (scalar)
            #pragma unroll
            for (int i = 0; i < 4; ++i) {
                int task = tid + i * 256;
                int u = task >> 4, dc = (task & 15) * 4;
                uint2 vvv = *(const uint2*)&V[base + (u0 + u) * rowStride + dc];
                Vt[dc + 0][u] = (u16)(vvv.x & 0xFFFF);
                Vt[dc + 1][u] = (u16)(vvv.x >> 16);
                Vt[dc + 2][u] = (u16)(vvv.y & 0xFFFF);
                Vt[dc + 3][u] = (u16)(vvv.y >> 16);
            }
            __syncthreads();

            // S = Q K^T  (per wave: 16 t-rows x 64 u)
            f32x4 s[4] = {};
            #pragma unroll
            for (int ks = 0; ks < 2; ++ks) {
                bf16x8 bk_[4];
                #pragma unroll
                for (int ns = 0; ns < 4; ++ns) {
                    const int R = ns * 16 + l16;
                    bk_[ns] = *(const bf16x8*)&Sh[(R * 8 + ((ks * 4 + quad) ^ (l16 & 7))) * 8];
                }
                #pragma unroll
                for (int ns = 0; ns < 4; ++ns)
                    s[ns] = __builtin_amdgcn_mfma_f32_16x16x32_bf16(qf[ks], bk_[ns], s[ns], 0, 0, 0);
            }
            __syncthreads();   // K reads done before P overwrites Sh

            // scale (+ mask only on diagonal tile)
            if (ui == qt) {
                #pragma unroll
                for (int ns = 0; ns < 4; ++ns)
                    #pragma unroll
                    for (int r = 0; r < 4; ++r) {
                        int trow = wv * 16 + quad * 4 + r;      // within tile
                        int ucol = ns * 16 + l16;
                        float v = s[ns][r] * 0.125f;
                        s[ns][r] = (ucol > trow) ? -1.0e30f : v;
                    }
            } else {
                #pragma unroll
                for (int ns = 0; ns < 4; ++ns)
                    #pragma unroll
                    for (int r = 0; r < 4; ++r)
                        s[ns][r] *= 0.125f;
            }
            // online softmax (wave-exclusive rows; reduce over l16)
            #pragma unroll
            for (int r = 0; r < 4; ++r) {
                float tmax = s[0][r];
                #pragma unroll
                for (int ns = 1; ns < 4; ++ns) tmax = fmaxf(tmax, s[ns][r]);
                #pragma unroll
                for (int off = 1; off < 16; off <<= 1)
                    tmax = fmaxf(tmax, __shfl_xor(tmax, off, 64));
                float mn = fmaxf(m_i[r], tmax);
                alpha[r] = __expf(fminf(m_i[r] - mn, 0.f));
                m_i[r] = mn;
                float rsum = 0.f;
                #pragma unroll
                for (int ns = 0; ns < 4; ++ns) {
                    float e = __expf(fminf(s[ns][r] - mn, 0.f));
                    s[ns][r] = e;
                    rsum += e;
                }
                #pragma unroll
                for (int off = 1; off < 16; off <<= 1)
                    rsum += __shfl_xor(rsum, off, 64);
                l_i[r] = l_i[r] * alpha[r] + rsum;
            }
            #pragma unroll
            for (int nd = 0; nd < 4; ++nd)
                #pragma unroll
                for (int r = 0; r < 4; ++r)
                    o[nd][r] *= alpha[r];
            // write P into Sh (swizzled layout so PV frag reads match)
            #pragma unroll
            for (int ns = 0; ns < 4; ++ns)
                #pragma unroll
                for (int r = 0; r < 4; ++r) {
                    const int row = wv * 16 + quad * 4 + r;
                    const int cu  = ns * 2 + (l16 >> 3);
                    Sh[(row * 8 + (cu ^ (row & 7))) * 8 + (l16 & 7)] = f2bf(s[ns][r]);
                }
            __syncthreads();
            // O += P @ V
            #pragma unroll
            for (int ks = 0; ks < 2; ++ks) {
                const int R = wv * 16 + l16;
                bf16x8 ap = *(const bf16x8*)&Sh[(R * 8 + ((ks * 4 + quad) ^ (l16 & 7))) * 8];
                bf16x8 bv_[4];
                #pragma unroll
                for (int nd = 0; nd < 4; ++nd)
                    bv_[nd] = *(const bf16x8*)&Vt[nd * 16 + l16][ks * 32 + quad * 8];
                #pragma unroll
                for (int nd = 0; nd < 4; ++nd)
                    o[nd] = __builtin_amdgcn_mfma_f32_16x16x32_bf16(ap, bv_[nd], o[nd], 0, 0, 0);
            }
        }

        // epilogue for this q-tile
        #pragma unroll
        for (int nd = 0; nd < 4; ++nd)
            #pragma unroll
            for (int r = 0; r < 4; ++r) {
                int t = t0 + wv * 16 + quad * 4 + r;
                int d = nd * 16 + l16;
                float val = o[nd][r] / l_i[r];
                int ym = (b * TT + t) * PP + p;
                Y[ym * 512 + h * 64 + d] = f2bf(val);
            }
    }
}

// ---------------------------------------------------------------------------
extern "C" void kernel_launch(void* const* d_in, const int* in_sizes, int n_in,
                              void* d_out, int out_size, void* d_ws, size_t ws_size,
                              hipStream_t stream) {
    const float* x  = (const float*)d_in[0];
    const float* qw = (const float*)d_in[1];
    const float* qb = (const float*)d_in[2];
    const float* kw = (const float*)d_in[3];
    const float* kb = (const float*)d_in[4];
    const float* vw = (const float*)d_in[5];
    const float* vb = (const float*)d_in[6];
    const float* pw = (const float*)d_in[7];

    // ws (35.7 MB): xb | wAll (qw,kw,vw,pw bf16) | Qb.
    // d_out (33.5 MB f32) hosts V (lower) + K (upper) as bf16; both dead
    // before the proj GEMM overwrites d_out. Y aliases Qb.
    u16* ws   = (u16*)d_ws;
    u16* xb   = ws;
    u16* wAll = ws + (size_t)MROWS * 512;
    u16* Qb   = wAll + 4 * 262144;
    u16* Vb   = (u16*)d_out;
    u16* Kb   = (u16*)d_out + (size_t)MROWS * 512;

    cvt_k<<<4096, 256, 0, stream>>>(x, xb);
    cvtw_k<<<dim3(128, 4), 256, 0, stream>>>(qw, kw, vw, pw, wAll);
    gemm_k<true><<<dim3(128, 12), 256, 0, stream>>>(xb, wAll, qb, kb, vb,
                                                    Qb, Kb, Vb, nullptr);
    attn_k<<<dim3(4, 256), 256, 0, stream>>>(Qb, Kb, Vb, Qb);
    gemm_k<false><<<dim3(128, 4), 256, 0, stream>>>(Qb, wAll + 3 * 262144,
                                                    nullptr, nullptr, nullptr,
                                                    nullptr, nullptr, nullptr,
                                                    (float*)d_out);
}